// Round 6
// baseline (731.695 us; speedup 1.0000x reference)
//
#include <hip/hip_runtime.h>
#include <cstdio>

#define BATCH 256
#define TSEQ  393
#define CH    128
#define FIN   3
#define TIN   800
#define KK    15
#define HID   150
#define NPAD  640      // interleaved gate dim: n = 4*j + gate, j<160 (j>=150 pad)
#define KPAD  160      // padded hidden dim for W_hh
#define NB    16       // batch rows per recurrence block
#define HALF_A 197
#define HALF_B 196
#define SLOTSTRIDE (16*10240)   // halves between consecutive slots

typedef _Float16 half_t;
typedef __attribute__((ext_vector_type(8))) _Float16 h8v;
typedef __attribute__((ext_vector_type(4))) _Float16 h4v;
typedef __attribute__((ext_vector_type(4))) float f4v;

__device__ inline float hsig(float x){ return fminf(fmaxf(fmaf(0.2f, x, 0.5f), 0.f), 1.f); }
__device__ inline float tanh_(float x){
  float e = __expf(2.f*x);
  return fmaf(-2.f, __builtin_amdgcn_rcpf(e + 1.f), 1.f);
}

#define DPPF(v, ctrl) __int_as_float(__builtin_amdgcn_mov_dpp(__float_as_int(v), ctrl, 0xF, 0xF, true))
#define XPOSE_PAIR(va, vb, om, CTRL) { float t_ = om ? va : vb; t_ = DPPF(t_, CTRL); va = om ? t_ : va; vb = om ? vb : t_; }

// ---------------- weight prep (fp32 -> f16, gate-interleaved rows) ----------------
__global__ void prep_wih(const float* __restrict__ wf, const float* __restrict__ wb,
                         half_t* __restrict__ out){
  int i = blockIdx.x*256 + threadIdx.x;          // 2*640*128
  if (i >= 2*NPAD*CH) return;
  int c = i & 127; int n = (i >> 7) % NPAD; int d = i / (NPAD*CH);
  const float* src = d ? wb : wf;
  float v = 0.f;
  if (n < 600){ int j = n >> 2, g = n & 3; v = src[(g*HID + j)*CH + c]; }
  out[i] = (half_t)v;
}
__global__ void prep_whh(const float* __restrict__ wf, const float* __restrict__ wb,
                         half_t* __restrict__ out){
  int i = blockIdx.x*256 + threadIdx.x;          // 2*640*160
  if (i >= 2*NPAD*KPAD) return;
  int kc = i % KPAD; int n = (i / KPAD) % NPAD; int d = i / (NPAD*KPAD);
  const float* src = d ? wb : wf;
  float v = 0.f;
  if (n < 600 && kc < HID){ int j = n >> 2, g = n & 3; v = src[(g*HID + j)*HID + kc]; }
  out[i] = (half_t)v;
}
__global__ void prep_bsum(const float* __restrict__ bihf, const float* __restrict__ bhhf,
                          const float* __restrict__ bihb, const float* __restrict__ bhhb,
                          float* __restrict__ out){
  int i = blockIdx.x*256 + threadIdx.x;          // 2*640
  if (i >= 2*NPAD) return;
  int n = i % NPAD; int d = i / NPAD;
  float v = 0.f;
  if (n < 600){ int j = n >> 2, g = n & 3; int r = g*HID + j;
    v = d ? (bihb[r] + bhhb[r]) : (bihf[r] + bhhf[r]); }
  out[i] = v;
}

// ---------------- conv1d + relu + maxpool2 -> xseq f16 [B][T][C] ----------------
#define CTT 32
__global__ __launch_bounds__(256) void conv_pool(const float* __restrict__ x,
                                                 const float* __restrict__ w,
                                                 const float* __restrict__ bias,
                                                 half_t* __restrict__ xseq){
  __shared__ float wl[CH*FIN*KK];
  __shared__ float xl[FIN][2*CTT + 14];
  int tid = threadIdx.x;
  int b = blockIdx.x, t0 = blockIdx.y*CTT;
  for (int i = tid; i < CH*FIN*KK; i += 256) wl[i] = w[i];
  int p0 = 2*t0;
  for (int i = tid; i < FIN*(2*CTT+14); i += 256){
    int f = i/(2*CTT+14), q = i%(2*CTT+14);
    int p = p0 + q;
    xl[f][q] = (p < TIN) ? x[((size_t)b*FIN + f)*TIN + p] : 0.f;
  }
  __syncthreads();
  int c = tid & 127, th = tid >> 7;
  float a0[16], a1[16];
  #pragma unroll
  for (int i=0;i<16;++i){ a0[i]=0.f; a1[i]=0.f; }
  #pragma unroll
  for (int f=0; f<FIN; ++f){
    float xv[46];
    #pragma unroll
    for (int q=0;q<46;++q) xv[q] = xl[f][th*32 + q];
    #pragma unroll
    for (int k=0;k<KK;++k){
      float ws = wl[c*FIN*KK + f*KK + k];
      #pragma unroll
      for (int i=0;i<16;++i){
        a0[i] = fmaf(xv[2*i+k],   ws, a0[i]);
        a1[i] = fmaf(xv[2*i+k+1], ws, a1[i]);
      }
    }
  }
  float bc = bias[c];
  #pragma unroll
  for (int i=0;i<16;++i){
    int t = t0 + th*16 + i;
    if (t < TSEQ){
      float v = fmaxf(fmaxf(a0[i], a1[i]) + bc, 0.f);
      xseq[((size_t)b*TSEQ + t)*CH + c] = (half_t)v;
    }
  }
}

// ---------------- x-projection: pre[d][slot][bt16][n640][b16] f16 ----------------
__global__ __launch_bounds__(512) void proj(const half_t* __restrict__ xseq,
                                            const half_t* __restrict__ wih,
                                            const float* __restrict__ bsum,
                                            half_t* __restrict__ pre,
                                            int off){
  int bt4 = blockIdx.x;       // 4 blocks of 64 batch rows
  int s   = blockIdx.y;
  int d   = blockIdx.z;
  int sg  = s + off;
  int t   = d ? (TSEQ-1 - sg) : sg;
  int tid = threadIdx.x, wv = tid >> 6, ln = tid & 63;
  int m = ln & 15, kg = ln >> 4;

  h8v bfr[5][4]; float bs[5];
  #pragma unroll
  for (int i = 0; i < 5; ++i){
    int n = (wv*5 + i)*16 + m;
    #pragma unroll
    for (int ks = 0; ks < 4; ++ks)
      bfr[i][ks] = *(const h8v*)(wih + ((size_t)d*NPAD + n)*CH + ks*32 + kg*8);
    bs[i] = bsum[d*NPAD + n];
  }
  #pragma unroll
  for (int ms = 0; ms < 4; ++ms){
    int b = bt4*64 + ms*16 + m;
    h8v ax[4];
    #pragma unroll
    for (int ks = 0; ks < 4; ++ks)
      ax[ks] = *(const h8v*)(xseq + ((size_t)b*TSEQ + t)*CH + ks*32 + kg*8);
    #pragma unroll
    for (int i = 0; i < 5; ++i){
      f4v acc = {bs[i], bs[i], bs[i], bs[i]};
      #pragma unroll
      for (int ks = 0; ks < 4; ++ks)
        acc = __builtin_amdgcn_mfma_f32_16x16x32_f16(ax[ks], bfr[i][ks], acc, 0, 0, 0);
      int n = (wv*5 + i)*16 + m;
      h4v hv = {(half_t)acc[0], (half_t)acc[1], (half_t)acc[2], (half_t)acc[3]};
      *(h4v*)(pre + (((size_t)d*HALF_A + s)*16 + (bt4*4 + ms))*10240 + n*16 + kg*4) = hv;
    }
  }
}

// ---------------- recurrence ----------------
// W_hh fragments pinned in AGPRs ("a" constraints); MFMAs via inline asm so the
// allocator cannot rematerialize/spill the weights (R4/R5: intrinsic path reloaded
// 200KB/block/step from L2 through L1 = 3200cy/step). Depth-2 pre prefetch.
__global__ __launch_bounds__(512, 2) void recur(const half_t* __restrict__ pre,
                                                const half_t* __restrict__ whh,
                                                float* __restrict__ pooled,
                                                float* __restrict__ stateC,
                                                half_t* __restrict__ stateH,
                                                int first, int last, int nsteps){
  __shared__ __align__(16) half_t hbuf[2*NB*168];   // [2][16][168]

  int tid = threadIdx.x, wv = tid >> 6, ln = tid & 63;
  int m = ln & 15, kg = ln >> 4;
  int bt = blockIdx.x, d = blockIdx.y;
  int b0 = bt*NB;
  int blk = d*16 + bt;
  bool o1 = (ln & 1), o2 = (ln & 2);

  // resident W_hh fragments, pinned in AGPRs
  h8v bA[5][5];
  #pragma unroll
  for (int i = 0; i < 5; ++i){
    int n = (wv*5 + i)*16 + m;
    #pragma unroll
    for (int ks = 0; ks < 5; ++ks){
      h8v w = *(const h8v*)(whh + ((size_t)d*NPAD + n)*KPAD + ks*32 + kg*8);
      asm volatile("" : "+a"(w));      // force into AGPR tuple
      bA[i][ks] = w;
    }
  }

  // per-lane cell/batch identity for gate phase
  int jc[5], bc_;
  bc_ = kg*4 + (m&3);
  #pragma unroll
  for (int T = 0; T < 5; ++T) jc[T] = 20*wv + 4*T + (m>>2);

  float c_reg[5], hm_reg[5];
  if (first){
    for (int i = tid; i < NB*168; i += 512) hbuf[i] = (half_t)0.f;
    for (int i = tid; i < NB*168; i += 512) hbuf[NB*168 + i] = (half_t)0.f;
    #pragma unroll
    for (int T = 0; T < 5; ++T){ c_reg[T] = 0.f; hm_reg[T] = -1e30f; }
  } else {
    for (int i = tid; i < NB*168; i += 512) hbuf[i] = stateH[(size_t)blk*NB*168 + i];
    for (int i = tid; i < NB*168; i += 512) hbuf[NB*168 + i] = (half_t)0.f;
    const float* sc = stateC + ((size_t)blk*512 + tid)*10;
    #pragma unroll
    for (int T = 0; T < 5; ++T){ c_reg[T] = sc[T]; hm_reg[T] = sc[5+T]; }
  }
  __syncthreads();

  const half_t* pb = pre + ((size_t)d*HALF_A*16 + bt)*10240;
  int pofl = wv*1280 + m*16 + kg*4;

  // depth-2 prefetch pipeline
  h4v curp[5], nA[5];
  #pragma unroll
  for (int T = 0; T < 5; ++T) curp[T] = *(const h4v*)(pb + pofl + T*256);
  {
    const half_t* p1 = pb + (size_t)(nsteps > 1 ? 1 : 0)*SLOTSTRIDE;
    #pragma unroll
    for (int T = 0; T < 5; ++T) nA[T] = *(const h4v*)(p1 + pofl + T*256);
  }

  int p = 0;
  #pragma unroll 1
  for (int s = 0; s < nsteps; ++s){
    int s2 = (s+2 < nsteps) ? s+2 : nsteps-1;
    const half_t* p2 = pb + (size_t)s2*SLOTSTRIDE;
    h4v nB[5];
    #pragma unroll
    for (int T = 0; T < 5; ++T) nB[T] = *(const h4v*)(p2 + pofl + T*256);

    // A fragments from h buffer p (b-major rows)
    const half_t* hrd = hbuf + p*NB*168 + m*168;
    h8v ah0 = *(const h8v*)(hrd + 0*32 + kg*8);
    h8v ah1 = *(const h8v*)(hrd + 1*32 + kg*8);
    h8v ah2 = *(const h8v*)(hrd + 2*32 + kg*8);
    h8v ah3 = *(const h8v*)(hrd + 3*32 + kg*8);
    h8v ah4 = *(const h8v*)(hrd + 4*32 + kg*8);

    f4v acc[5];
    #pragma unroll
    for (int T = 0; T < 5; ++T) acc[T] = (f4v){0.f, 0.f, 0.f, 0.f};

    // k0,k1 for all 5 T (5-way interleaved chains)
    asm volatile(
      "s_nop 1\n\t"
      "v_mfma_f32_16x16x32_f16 %0, %5, %7, %0\n\t"
      "v_mfma_f32_16x16x32_f16 %1, %5, %9, %1\n\t"
      "v_mfma_f32_16x16x32_f16 %2, %5, %11, %2\n\t"
      "v_mfma_f32_16x16x32_f16 %3, %5, %13, %3\n\t"
      "v_mfma_f32_16x16x32_f16 %4, %5, %15, %4\n\t"
      "v_mfma_f32_16x16x32_f16 %0, %6, %8, %0\n\t"
      "v_mfma_f32_16x16x32_f16 %1, %6, %10, %1\n\t"
      "v_mfma_f32_16x16x32_f16 %2, %6, %12, %2\n\t"
      "v_mfma_f32_16x16x32_f16 %3, %6, %14, %3\n\t"
      "v_mfma_f32_16x16x32_f16 %4, %6, %16, %4"
      : "+v"(acc[0]), "+v"(acc[1]), "+v"(acc[2]), "+v"(acc[3]), "+v"(acc[4])
      : "v"(ah0), "v"(ah1),
        "a"(bA[0][0]), "a"(bA[0][1]),
        "a"(bA[1][0]), "a"(bA[1][1]),
        "a"(bA[2][0]), "a"(bA[2][1]),
        "a"(bA[3][0]), "a"(bA[3][1]),
        "a"(bA[4][0]), "a"(bA[4][1]));
    __builtin_amdgcn_sched_barrier(0);
    // k2,k3,k4 for all 5 T; trailing nops cover MFMA->VALU read hazard
    asm volatile(
      "v_mfma_f32_16x16x32_f16 %0, %5, %8, %0\n\t"
      "v_mfma_f32_16x16x32_f16 %1, %5, %11, %1\n\t"
      "v_mfma_f32_16x16x32_f16 %2, %5, %14, %2\n\t"
      "v_mfma_f32_16x16x32_f16 %3, %5, %17, %3\n\t"
      "v_mfma_f32_16x16x32_f16 %4, %5, %20, %4\n\t"
      "v_mfma_f32_16x16x32_f16 %0, %6, %9, %0\n\t"
      "v_mfma_f32_16x16x32_f16 %1, %6, %12, %1\n\t"
      "v_mfma_f32_16x16x32_f16 %2, %6, %15, %2\n\t"
      "v_mfma_f32_16x16x32_f16 %3, %6, %18, %3\n\t"
      "v_mfma_f32_16x16x32_f16 %4, %6, %21, %4\n\t"
      "v_mfma_f32_16x16x32_f16 %0, %7, %10, %0\n\t"
      "v_mfma_f32_16x16x32_f16 %1, %7, %13, %1\n\t"
      "v_mfma_f32_16x16x32_f16 %2, %7, %16, %2\n\t"
      "v_mfma_f32_16x16x32_f16 %3, %7, %19, %3\n\t"
      "v_mfma_f32_16x16x32_f16 %4, %7, %22, %4\n\t"
      "s_nop 7\n\t"
      "s_nop 7"
      : "+v"(acc[0]), "+v"(acc[1]), "+v"(acc[2]), "+v"(acc[3]), "+v"(acc[4])
      : "v"(ah2), "v"(ah3), "v"(ah4),
        "a"(bA[0][2]), "a"(bA[0][3]), "a"(bA[0][4]),
        "a"(bA[1][2]), "a"(bA[1][3]), "a"(bA[1][4]),
        "a"(bA[2][2]), "a"(bA[2][3]), "a"(bA[2][4]),
        "a"(bA[3][2]), "a"(bA[3][3]), "a"(bA[3][4]),
        "a"(bA[4][2]), "a"(bA[4][3]), "a"(bA[4][4]));
    __builtin_amdgcn_sched_barrier(0);

    half_t* hwr = hbuf + (p^1)*NB*168 + bc_*168;
    #pragma unroll
    for (int T = 0; T < 5; ++T){
      float v0 = acc[T][0] + (float)curp[T][0];
      float v1 = acc[T][1] + (float)curp[T][1];
      float v2 = acc[T][2] + (float)curp[T][2];
      float v3 = acc[T][3] + (float)curp[T][3];
      // quad 4x4 transpose: lane ends with (i,f,g,o) of its own cell
      XPOSE_PAIR(v0, v1, o1, 0xB1);
      XPOSE_PAIR(v2, v3, o1, 0xB1);
      XPOSE_PAIR(v0, v2, o2, 0x4E);
      XPOSE_PAIR(v1, v3, o2, 0x4E);
      float cn = hsig(v1)*c_reg[T] + hsig(v0)*tanh_(v2);
      float hn = hsig(v3)*tanh_(cn);
      c_reg[T] = cn;
      hm_reg[T] = fmaxf(hm_reg[T], hn);
      hwr[jc[T]] = (half_t)hn;
    }

    #pragma unroll
    for (int T = 0; T < 5; ++T) curp[T] = nA[T];
    #pragma unroll
    for (int T = 0; T < 5; ++T) nA[T] = nB[T];

    // lgkm-only barrier: h writes drained, global prefetch NOT force-drained
    asm volatile("s_waitcnt lgkmcnt(0)" ::: "memory");
    __builtin_amdgcn_s_barrier();
    __builtin_amdgcn_sched_barrier(0);
    p ^= 1;
  }

  if (!last){
    for (int i = tid; i < NB*168; i += 512) stateH[(size_t)blk*NB*168 + i] = hbuf[p*NB*168 + i];
    float* sc = stateC + ((size_t)blk*512 + tid)*10;
    #pragma unroll
    for (int T = 0; T < 5; ++T){ sc[T] = c_reg[T]; sc[5+T] = hm_reg[T]; }
  } else {
    #pragma unroll
    for (int T = 0; T < 5; ++T){
      if (jc[T] < HID) pooled[(size_t)(b0 + bc_)*300 + d*HID + jc[T]] = hm_reg[T];
    }
  }
}

// ---------------- final MLP + softmax ----------------
__global__ __launch_bounds__(256) void fc(const float* __restrict__ pooled,
                                          const float* __restrict__ w1, const float* __restrict__ b1,
                                          const float* __restrict__ w2, const float* __restrict__ b2,
                                          float* __restrict__ out){
  __shared__ float prow[300];
  __shared__ float ps[64][5];
  __shared__ float z[52];
  __shared__ float lg[12];
  int b = blockIdx.x, tid = threadIdx.x;
  for (int i = tid; i < 300; i += 256) prow[i] = pooled[(size_t)b*300 + i];
  __syncthreads();
  int j = tid & 63, seg = tid >> 6;
  float a = 0.f;
  if (j < 50){
    const float* wr = w1 + (size_t)j*300 + seg*75;
    const float* pr = prow + seg*75;
    #pragma unroll 5
    for (int k = 0; k < 75; ++k) a = fmaf(pr[k], wr[k], a);
  }
  ps[j][seg] = a;
  __syncthreads();
  if (tid < 50) z[tid] = fmaxf(ps[tid][0]+ps[tid][1]+ps[tid][2]+ps[tid][3] + b1[tid], 0.f);
  __syncthreads();
  if (tid < 10){
    float a2 = b2[tid];
    for (int k = 0; k < 50; ++k) a2 = fmaf(z[k], w2[tid*50 + k], a2);
    lg[tid] = a2;
  }
  __syncthreads();
  if (tid < 10){
    float mx = lg[0];
    #pragma unroll
    for (int k = 1; k < 10; ++k) mx = fmaxf(mx, lg[k]);
    float ssum = 0.f;
    #pragma unroll
    for (int k = 0; k < 10; ++k) ssum += __expf(lg[k] - mx);
    out[(size_t)b*10 + tid] = __expf(lg[tid] - mx) / ssum;
  }
}

extern "C" void kernel_launch(void* const* d_in, const int* in_sizes, int n_in,
                              void* d_out, int out_size, void* d_ws, size_t ws_size,
                              hipStream_t stream) {
  const float* x      = (const float*)d_in[0];
  const float* conv_w = (const float*)d_in[1];
  const float* conv_b = (const float*)d_in[2];
  const float* w_ih_f = (const float*)d_in[3];
  const float* w_hh_f = (const float*)d_in[4];
  const float* b_ih_f = (const float*)d_in[5];
  const float* b_hh_f = (const float*)d_in[6];
  const float* w_ih_b = (const float*)d_in[7];
  const float* w_hh_b = (const float*)d_in[8];
  const float* b_ih_b = (const float*)d_in[9];
  const float* b_hh_b = (const float*)d_in[10];
  const float* l1w = (const float*)d_in[11];
  const float* l1b = (const float*)d_in[12];
  const float* l2w = (const float*)d_in[13];
  const float* l2b = (const float*)d_in[14];
  float* out = (float*)d_out;

  char* ws = (char*)d_ws;
  size_t off = 0;
  auto alloc = [&](size_t bytes){ size_t o = off; off += (bytes + 255) & ~(size_t)255; return o; };
  size_t xseq_o = alloc((size_t)BATCH*TSEQ*CH*2);
  size_t pre_o  = alloc((size_t)2*HALF_A*16*10240*2);
  size_t wih_o  = alloc((size_t)2*NPAD*CH*2);
  size_t whh_o  = alloc((size_t)2*NPAD*KPAD*2);
  size_t bs_o   = alloc((size_t)2*NPAD*4);
  size_t pool_o = alloc((size_t)BATCH*300*4);
  size_t stc_o  = alloc((size_t)32*512*10*4);
  size_t sth_o  = alloc((size_t)32*NB*168*2);
  if (off > ws_size){
    fprintf(stderr, "[cnnblstm] WS TOO SMALL: need %zu have %zu\n", off, ws_size);
    return;
  }
  half_t* xseq_p = (half_t*)(ws + xseq_o);
  half_t* pre_p  = (half_t*)(ws + pre_o);
  half_t* wih_p  = (half_t*)(ws + wih_o);
  half_t* whh_p  = (half_t*)(ws + whh_o);
  float*  bs_p   = (float*)(ws + bs_o);
  float*  pool_p = (float*)(ws + pool_o);
  float*  stc_p  = (float*)(ws + stc_o);
  half_t* sth_p  = (half_t*)(ws + sth_o);

  prep_wih <<<(2*NPAD*CH + 255)/256, 256, 0, stream>>>(w_ih_f, w_ih_b, wih_p);
  prep_whh <<<(2*NPAD*KPAD + 255)/256, 256, 0, stream>>>(w_hh_f, w_hh_b, whh_p);
  prep_bsum<<<(2*NPAD + 255)/256, 256, 0, stream>>>(b_ih_f, b_hh_f, b_ih_b, b_hh_b, bs_p);
  conv_pool<<<dim3(BATCH, (TSEQ + CTT - 1)/CTT), 256, 0, stream>>>(x, conv_w, conv_b, xseq_p);

  proj <<<dim3(4, HALF_A, 2), 512, 0, stream>>>(xseq_p, wih_p, bs_p, pre_p, 0);
  recur<<<dim3(16, 2), 512, 0, stream>>>(pre_p, whh_p, pool_p, stc_p, sth_p, 1, 0, HALF_A);
  proj <<<dim3(4, HALF_B, 2), 512, 0, stream>>>(xseq_p, wih_p, bs_p, pre_p, HALF_A);
  recur<<<dim3(16, 2), 512, 0, stream>>>(pre_p, whh_p, pool_p, stc_p, sth_p, 0, 1, HALF_B);

  fc<<<BATCH, 256, 0, stream>>>(pool_p, l1w, l1b, l2w, l2b, out);
}

// Round 7
// 714.419 us; speedup vs baseline: 1.0242x; 1.0242x over previous
//
#include <hip/hip_runtime.h>
#include <cstdio>

#define BATCH 256
#define TSEQ  393
#define CH    128
#define FIN   3
#define TIN   800
#define KK    15
#define HID   150
#define NPAD  640      // interleaved gate dim: n = 4*j + gate, j<160 (j>=150 pad)
#define KPAD  160      // padded hidden dim for W_hh
#define NB    16       // batch rows per recurrence block
#define HALF_A 197
#define HALF_B 196
#define SLOTSTRIDE (16*10240)   // halves between consecutive slots

typedef _Float16 half_t;
typedef __attribute__((ext_vector_type(8))) _Float16 h8v;
typedef __attribute__((ext_vector_type(4))) _Float16 h4v;
typedef __attribute__((ext_vector_type(4))) float f4v;

__device__ inline float hsig(float x){ return fminf(fmaxf(fmaf(0.2f, x, 0.5f), 0.f), 1.f); }
__device__ inline float tanh_(float x){
  float e = __expf(2.f*x);
  return fmaf(-2.f, __builtin_amdgcn_rcpf(e + 1.f), 1.f);
}

#define DPPF(v, ctrl) __int_as_float(__builtin_amdgcn_mov_dpp(__float_as_int(v), ctrl, 0xF, 0xF, true))
#define XPOSE_PAIR(va, vb, om, CTRL) { float t_ = om ? va : vb; t_ = DPPF(t_, CTRL); va = om ? t_ : va; vb = om ? vb : t_; }

// ---------------- weight prep (fp32 -> f16, gate-interleaved rows) ----------------
__global__ void prep_wih(const float* __restrict__ wf, const float* __restrict__ wb,
                         half_t* __restrict__ out){
  int i = blockIdx.x*256 + threadIdx.x;          // 2*640*128
  if (i >= 2*NPAD*CH) return;
  int c = i & 127; int n = (i >> 7) % NPAD; int d = i / (NPAD*CH);
  const float* src = d ? wb : wf;
  float v = 0.f;
  if (n < 600){ int j = n >> 2, g = n & 3; v = src[(g*HID + j)*CH + c]; }
  out[i] = (half_t)v;
}
__global__ void prep_whh(const float* __restrict__ wf, const float* __restrict__ wb,
                         half_t* __restrict__ out){
  int i = blockIdx.x*256 + threadIdx.x;          // 2*640*160
  if (i >= 2*NPAD*KPAD) return;
  int kc = i % KPAD; int n = (i / KPAD) % NPAD; int d = i / (NPAD*KPAD);
  const float* src = d ? wb : wf;
  float v = 0.f;
  if (n < 600 && kc < HID){ int j = n >> 2, g = n & 3; v = src[(g*HID + j)*HID + kc]; }
  out[i] = (half_t)v;
}
__global__ void prep_bsum(const float* __restrict__ bihf, const float* __restrict__ bhhf,
                          const float* __restrict__ bihb, const float* __restrict__ bhhb,
                          float* __restrict__ out){
  int i = blockIdx.x*256 + threadIdx.x;          // 2*640
  if (i >= 2*NPAD) return;
  int n = i % NPAD; int d = i / NPAD;
  float v = 0.f;
  if (n < 600){ int j = n >> 2, g = n & 3; int r = g*HID + j;
    v = d ? (bihb[r] + bhhb[r]) : (bihf[r] + bhhf[r]); }
  out[i] = v;
}

// ---------------- conv1d + relu + maxpool2 -> xseq f16 [B][T][C] ----------------
#define CTT 32
__global__ __launch_bounds__(256) void conv_pool(const float* __restrict__ x,
                                                 const float* __restrict__ w,
                                                 const float* __restrict__ bias,
                                                 half_t* __restrict__ xseq){
  __shared__ float wl[CH*FIN*KK];
  __shared__ float xl[FIN][2*CTT + 14];
  int tid = threadIdx.x;
  int b = blockIdx.x, t0 = blockIdx.y*CTT;
  for (int i = tid; i < CH*FIN*KK; i += 256) wl[i] = w[i];
  int p0 = 2*t0;
  for (int i = tid; i < FIN*(2*CTT+14); i += 256){
    int f = i/(2*CTT+14), q = i%(2*CTT+14);
    int p = p0 + q;
    xl[f][q] = (p < TIN) ? x[((size_t)b*FIN + f)*TIN + p] : 0.f;
  }
  __syncthreads();
  int c = tid & 127, th = tid >> 7;
  float a0[16], a1[16];
  #pragma unroll
  for (int i=0;i<16;++i){ a0[i]=0.f; a1[i]=0.f; }
  #pragma unroll
  for (int f=0; f<FIN; ++f){
    float xv[46];
    #pragma unroll
    for (int q=0;q<46;++q) xv[q] = xl[f][th*32 + q];
    #pragma unroll
    for (int k=0;k<KK;++k){
      float ws = wl[c*FIN*KK + f*KK + k];
      #pragma unroll
      for (int i=0;i<16;++i){
        a0[i] = fmaf(xv[2*i+k],   ws, a0[i]);
        a1[i] = fmaf(xv[2*i+k+1], ws, a1[i]);
      }
    }
  }
  float bc = bias[c];
  #pragma unroll
  for (int i=0;i<16;++i){
    int t = t0 + th*16 + i;
    if (t < TSEQ){
      float v = fmaxf(fmaxf(a0[i], a1[i]) + bc, 0.f);
      xseq[((size_t)b*TSEQ + t)*CH + c] = (half_t)v;
    }
  }
}

// ---------------- x-projection: pre[d][slot][bt16][n640][b16] f16 ----------------
__global__ __launch_bounds__(512) void proj(const half_t* __restrict__ xseq,
                                            const half_t* __restrict__ wih,
                                            const float* __restrict__ bsum,
                                            half_t* __restrict__ pre,
                                            int off){
  int bt4 = blockIdx.x;       // 4 blocks of 64 batch rows
  int s   = blockIdx.y;
  int d   = blockIdx.z;
  int sg  = s + off;
  int t   = d ? (TSEQ-1 - sg) : sg;
  int tid = threadIdx.x, wv = tid >> 6, ln = tid & 63;
  int m = ln & 15, kg = ln >> 4;

  h8v bfr[5][4]; float bs[5];
  #pragma unroll
  for (int i = 0; i < 5; ++i){
    int n = (wv*5 + i)*16 + m;
    #pragma unroll
    for (int ks = 0; ks < 4; ++ks)
      bfr[i][ks] = *(const h8v*)(wih + ((size_t)d*NPAD + n)*CH + ks*32 + kg*8);
    bs[i] = bsum[d*NPAD + n];
  }
  #pragma unroll
  for (int ms = 0; ms < 4; ++ms){
    int b = bt4*64 + ms*16 + m;
    h8v ax[4];
    #pragma unroll
    for (int ks = 0; ks < 4; ++ks)
      ax[ks] = *(const h8v*)(xseq + ((size_t)b*TSEQ + t)*CH + ks*32 + kg*8);
    #pragma unroll
    for (int i = 0; i < 5; ++i){
      f4v acc = {bs[i], bs[i], bs[i], bs[i]};
      #pragma unroll
      for (int ks = 0; ks < 4; ++ks)
        acc = __builtin_amdgcn_mfma_f32_16x16x32_f16(ax[ks], bfr[i][ks], acc, 0, 0, 0);
      int n = (wv*5 + i)*16 + m;
      h4v hv = {(half_t)acc[0], (half_t)acc[1], (half_t)acc[2], (half_t)acc[3]};
      *(h4v*)(pre + (((size_t)d*HALF_A + s)*16 + (bt4*4 + ms))*10240 + n*16 + kg*4) = hv;
    }
  }
}

// ---------------- recurrence ----------------
// W_hh pinned in PHYSICAL AGPRs a0..a99 via v_accvgpr_write at init; per-step
// MFMAs are single-line asm referencing literal a[N:N+3] ranges. No virtual
// weight values exist => allocator cannot spill/rematerialize them (R4/R5/R6
// all failed with virtual-reg pinning: ~3200cy/step of L1 weight re-reads).
#define PIN4(R0,R1,R2,R3, V) asm volatile( \
  "v_accvgpr_write_b32 " R0 ", %0\n\t" \
  "v_accvgpr_write_b32 " R1 ", %1\n\t" \
  "v_accvgpr_write_b32 " R2 ", %2\n\t" \
  "v_accvgpr_write_b32 " R3 ", %3" \
  :: "v"(V[0]), "v"(V[1]), "v"(V[2]), "v"(V[3]) : R0, R1, R2, R3)

#define LP(I,KS, R0,R1,R2,R3) { \
  h8v w_ = *(const h8v*)(whh + ((size_t)d*NPAD + ((wv*5+(I))*16+m))*KPAD + (KS)*32 + kg*8); \
  f4v wf_; __builtin_memcpy(&wf_, &w_, 16); \
  PIN4(R0,R1,R2,R3, wf_); }

#define MF0(ACC, AH, AR) asm volatile("v_mfma_f32_16x16x32_f16 %0, %1, " AR ", 0"  : "=v"(ACC) : "v"(AH))
#define MF(ACC, AH, AR)  asm volatile("v_mfma_f32_16x16x32_f16 %0, %1, " AR ", %0" : "+v"(ACC) : "v"(AH))

#define ACLOBS "a0","a1","a2","a3","a4","a5","a6","a7","a8","a9",\
"a10","a11","a12","a13","a14","a15","a16","a17","a18","a19",\
"a20","a21","a22","a23","a24","a25","a26","a27","a28","a29",\
"a30","a31","a32","a33","a34","a35","a36","a37","a38","a39",\
"a40","a41","a42","a43","a44","a45","a46","a47","a48","a49",\
"a50","a51","a52","a53","a54","a55","a56","a57","a58","a59",\
"a60","a61","a62","a63","a64","a65","a66","a67","a68","a69",\
"a70","a71","a72","a73","a74","a75","a76","a77","a78","a79",\
"a80","a81","a82","a83","a84","a85","a86","a87","a88","a89",\
"a90","a91","a92","a93","a94","a95","a96","a97","a98","a99"

__global__ __launch_bounds__(512, 2) void recur(const half_t* __restrict__ pre,
                                                const half_t* __restrict__ whh,
                                                float* __restrict__ pooled,
                                                float* __restrict__ stateC,
                                                half_t* __restrict__ stateH,
                                                int first, int last, int nsteps){
  __shared__ __align__(16) half_t hbuf[2*NB*168];   // [2][16][168]

  int tid = threadIdx.x, wv = tid >> 6, ln = tid & 63;
  int m = ln & 15, kg = ln >> 4;
  int bt = blockIdx.x, d = blockIdx.y;
  int b0 = bt*NB;
  int blk = d*16 + bt;
  bool o1 = (ln & 1), o2 = (ln & 2);

  // pin W_hh fragments into physical AGPRs: frag(I,KS) -> a[20I+4KS .. +3]
  LP(0,0,"a0","a1","a2","a3")    LP(0,1,"a4","a5","a6","a7")    LP(0,2,"a8","a9","a10","a11")
  LP(0,3,"a12","a13","a14","a15") LP(0,4,"a16","a17","a18","a19")
  LP(1,0,"a20","a21","a22","a23") LP(1,1,"a24","a25","a26","a27") LP(1,2,"a28","a29","a30","a31")
  LP(1,3,"a32","a33","a34","a35") LP(1,4,"a36","a37","a38","a39")
  LP(2,0,"a40","a41","a42","a43") LP(2,1,"a44","a45","a46","a47") LP(2,2,"a48","a49","a50","a51")
  LP(2,3,"a52","a53","a54","a55") LP(2,4,"a56","a57","a58","a59")
  LP(3,0,"a60","a61","a62","a63") LP(3,1,"a64","a65","a66","a67") LP(3,2,"a68","a69","a70","a71")
  LP(3,3,"a72","a73","a74","a75") LP(3,4,"a76","a77","a78","a79")
  LP(4,0,"a80","a81","a82","a83") LP(4,1,"a84","a85","a86","a87") LP(4,2,"a88","a89","a90","a91")
  LP(4,3,"a92","a93","a94","a95") LP(4,4,"a96","a97","a98","a99")

  // per-lane cell/batch identity for gate phase
  int jc[5], bc_;
  bc_ = kg*4 + (m&3);
  #pragma unroll
  for (int T = 0; T < 5; ++T) jc[T] = 20*wv + 4*T + (m>>2);

  float c_reg[5], hm_reg[5];
  if (first){
    for (int i = tid; i < NB*168; i += 512) hbuf[i] = (half_t)0.f;
    for (int i = tid; i < NB*168; i += 512) hbuf[NB*168 + i] = (half_t)0.f;
    #pragma unroll
    for (int T = 0; T < 5; ++T){ c_reg[T] = 0.f; hm_reg[T] = -1e30f; }
  } else {
    for (int i = tid; i < NB*168; i += 512) hbuf[i] = stateH[(size_t)blk*NB*168 + i];
    for (int i = tid; i < NB*168; i += 512) hbuf[NB*168 + i] = (half_t)0.f;
    const float* sc = stateC + ((size_t)blk*512 + tid)*10;
    #pragma unroll
    for (int T = 0; T < 5; ++T){ c_reg[T] = sc[T]; hm_reg[T] = sc[5+T]; }
  }
  __syncthreads();

  const half_t* pb = pre + ((size_t)d*HALF_A*16 + bt)*10240;
  int pofl = wv*1280 + m*16 + kg*4;

  // depth-2 prefetch pipeline
  h4v curp[5], nA[5];
  #pragma unroll
  for (int T = 0; T < 5; ++T) curp[T] = *(const h4v*)(pb + pofl + T*256);
  {
    const half_t* p1 = pb + (size_t)(nsteps > 1 ? 1 : 0)*SLOTSTRIDE;
    #pragma unroll
    for (int T = 0; T < 5; ++T) nA[T] = *(const h4v*)(p1 + pofl + T*256);
  }

  int p = 0;
  #pragma unroll 1
  for (int s = 0; s < nsteps; ++s){
    int s2 = (s+2 < nsteps) ? s+2 : nsteps-1;
    const half_t* p2 = pb + (size_t)s2*SLOTSTRIDE;
    h4v nB[5];
    #pragma unroll
    for (int T = 0; T < 5; ++T) nB[T] = *(const h4v*)(p2 + pofl + T*256);

    // A fragments from h buffer p (b-major rows)
    const half_t* hrd = hbuf + p*NB*168 + m*168;
    h8v ah0 = *(const h8v*)(hrd + 0*32 + kg*8);
    h8v ah1 = *(const h8v*)(hrd + 1*32 + kg*8);
    h8v ah2 = *(const h8v*)(hrd + 2*32 + kg*8);
    h8v ah3 = *(const h8v*)(hrd + 3*32 + kg*8);
    h8v ah4 = *(const h8v*)(hrd + 4*32 + kg*8);

    f4v acc0, acc1, acc2, acc3, acc4;
    // ks-major, 5 independent chains (same-acc MFMAs 5 apart)
    MF0(acc0, ah0, "a[0:3]");   MF0(acc1, ah0, "a[20:23]"); MF0(acc2, ah0, "a[40:43]");
    MF0(acc3, ah0, "a[60:63]"); MF0(acc4, ah0, "a[80:83]");
    MF (acc0, ah1, "a[4:7]");   MF (acc1, ah1, "a[24:27]"); MF (acc2, ah1, "a[44:47]");
    MF (acc3, ah1, "a[64:67]"); MF (acc4, ah1, "a[84:87]");
    MF (acc0, ah2, "a[8:11]");  MF (acc1, ah2, "a[28:31]"); MF (acc2, ah2, "a[48:51]");
    MF (acc3, ah2, "a[68:71]"); MF (acc4, ah2, "a[88:91]");
    MF (acc0, ah3, "a[12:15]"); MF (acc1, ah3, "a[32:35]"); MF (acc2, ah3, "a[52:55]");
    MF (acc3, ah3, "a[72:75]"); MF (acc4, ah3, "a[92:95]");
    MF (acc0, ah4, "a[16:19]"); MF (acc1, ah4, "a[36:39]"); MF (acc2, ah4, "a[56:59]");
    MF (acc3, ah4, "a[76:79]"); MF (acc4, ah4, "a[96:99]");
    // fence MFMA->VALU read hazard; operands force ordering before gate math
    asm volatile("s_nop 7\n\ts_nop 7"
                 : "+v"(acc0), "+v"(acc1), "+v"(acc2), "+v"(acc3), "+v"(acc4));

    f4v acc[5] = {acc0, acc1, acc2, acc3, acc4};
    half_t* hwr = hbuf + (p^1)*NB*168 + bc_*168;
    #pragma unroll
    for (int T = 0; T < 5; ++T){
      float v0 = acc[T][0] + (float)curp[T][0];
      float v1 = acc[T][1] + (float)curp[T][1];
      float v2 = acc[T][2] + (float)curp[T][2];
      float v3 = acc[T][3] + (float)curp[T][3];
      // quad 4x4 transpose: lane ends with (i,f,g,o) of its own cell
      XPOSE_PAIR(v0, v1, o1, 0xB1);
      XPOSE_PAIR(v2, v3, o1, 0xB1);
      XPOSE_PAIR(v0, v2, o2, 0x4E);
      XPOSE_PAIR(v1, v3, o2, 0x4E);
      float cn = hsig(v1)*c_reg[T] + hsig(v0)*tanh_(v2);
      float hn = hsig(v3)*tanh_(cn);
      c_reg[T] = cn;
      hm_reg[T] = fmaxf(hm_reg[T], hn);
      hwr[jc[T]] = (half_t)hn;
    }

    #pragma unroll
    for (int T = 0; T < 5; ++T) curp[T] = nA[T];
    #pragma unroll
    for (int T = 0; T < 5; ++T) nA[T] = nB[T];

    // lgkm-only barrier (global prefetch stays in flight); re-clobber a0..a99
    // each step so the allocator never parks spills in the weight AGPRs.
    asm volatile("s_waitcnt lgkmcnt(0)" ::: "memory", ACLOBS);
    __builtin_amdgcn_s_barrier();
    __builtin_amdgcn_sched_barrier(0);
    p ^= 1;
  }

  if (!last){
    for (int i = tid; i < NB*168; i += 512) stateH[(size_t)blk*NB*168 + i] = hbuf[p*NB*168 + i];
    float* sc = stateC + ((size_t)blk*512 + tid)*10;
    #pragma unroll
    for (int T = 0; T < 5; ++T){ sc[T] = c_reg[T]; sc[5+T] = hm_reg[T]; }
  } else {
    #pragma unroll
    for (int T = 0; T < 5; ++T){
      if (jc[T] < HID) pooled[(size_t)(b0 + bc_)*300 + d*HID + jc[T]] = hm_reg[T];
    }
  }
}

// ---------------- final MLP + softmax ----------------
__global__ __launch_bounds__(256) void fc(const float* __restrict__ pooled,
                                          const float* __restrict__ w1, const float* __restrict__ b1,
                                          const float* __restrict__ w2, const float* __restrict__ b2,
                                          float* __restrict__ out){
  __shared__ float prow[300];
  __shared__ float ps[64][5];
  __shared__ float z[52];
  __shared__ float lg[12];
  int b = blockIdx.x, tid = threadIdx.x;
  for (int i = tid; i < 300; i += 256) prow[i] = pooled[(size_t)b*300 + i];
  __syncthreads();
  int j = tid & 63, seg = tid >> 6;
  float a = 0.f;
  if (j < 50){
    const float* wr = w1 + (size_t)j*300 + seg*75;
    const float* pr = prow + seg*75;
    #pragma unroll 5
    for (int k = 0; k < 75; ++k) a = fmaf(pr[k], wr[k], a);
  }
  ps[j][seg] = a;
  __syncthreads();
  if (tid < 50) z[tid] = fmaxf(ps[tid][0]+ps[tid][1]+ps[tid][2]+ps[tid][3] + b1[tid], 0.f);
  __syncthreads();
  if (tid < 10){
    float a2 = b2[tid];
    for (int k = 0; k < 50; ++k) a2 = fmaf(z[k], w2[tid*50 + k], a2);
    lg[tid] = a2;
  }
  __syncthreads();
  if (tid < 10){
    float mx = lg[0];
    #pragma unroll
    for (int k = 1; k < 10; ++k) mx = fmaxf(mx, lg[k]);
    float ssum = 0.f;
    #pragma unroll
    for (int k = 0; k < 10; ++k) ssum += __expf(lg[k] - mx);
    out[(size_t)b*10 + tid] = __expf(lg[tid] - mx) / ssum;
  }
}

extern "C" void kernel_launch(void* const* d_in, const int* in_sizes, int n_in,
                              void* d_out, int out_size, void* d_ws, size_t ws_size,
                              hipStream_t stream) {
  const float* x      = (const float*)d_in[0];
  const float* conv_w = (const float*)d_in[1];
  const float* conv_b = (const float*)d_in[2];
  const float* w_ih_f = (const float*)d_in[3];
  const float* w_hh_f = (const float*)d_in[4];
  const float* b_ih_f = (const float*)d_in[5];
  const float* b_hh_f = (const float*)d_in[6];
  const float* w_ih_b = (const float*)d_in[7];
  const float* w_hh_b = (const float*)d_in[8];
  const float* b_ih_b = (const float*)d_in[9];
  const float* b_hh_b = (const float*)d_in[10];
  const float* l1w = (const float*)d_in[11];
  const float* l1b = (const float*)d_in[12];
  const float* l2w = (const float*)d_in[13];
  const float* l2b = (const float*)d_in[14];
  float* out = (float*)d_out;

  char* ws = (char*)d_ws;
  size_t off = 0;
  auto alloc = [&](size_t bytes){ size_t o = off; off += (bytes + 255) & ~(size_t)255; return o; };
  size_t xseq_o = alloc((size_t)BATCH*TSEQ*CH*2);
  size_t pre_o  = alloc((size_t)2*HALF_A*16*10240*2);
  size_t wih_o  = alloc((size_t)2*NPAD*CH*2);
  size_t whh_o  = alloc((size_t)2*NPAD*KPAD*2);
  size_t bs_o   = alloc((size_t)2*NPAD*4);
  size_t pool_o = alloc((size_t)BATCH*300*4);
  size_t stc_o  = alloc((size_t)32*512*10*4);
  size_t sth_o  = alloc((size_t)32*NB*168*2);
  if (off > ws_size){
    fprintf(stderr, "[cnnblstm] WS TOO SMALL: need %zu have %zu\n", off, ws_size);
    return;
  }
  half_t* xseq_p = (half_t*)(ws + xseq_o);
  half_t* pre_p  = (half_t*)(ws + pre_o);
  half_t* wih_p  = (half_t*)(ws + wih_o);
  half_t* whh_p  = (half_t*)(ws + whh_o);
  float*  bs_p   = (float*)(ws + bs_o);
  float*  pool_p = (float*)(ws + pool_o);
  float*  stc_p  = (float*)(ws + stc_o);
  half_t* sth_p  = (half_t*)(ws + sth_o);

  prep_wih <<<(2*NPAD*CH + 255)/256, 256, 0, stream>>>(w_ih_f, w_ih_b, wih_p);
  prep_whh <<<(2*NPAD*KPAD + 255)/256, 256, 0, stream>>>(w_hh_f, w_hh_b, whh_p);
  prep_bsum<<<(2*NPAD + 255)/256, 256, 0, stream>>>(b_ih_f, b_hh_f, b_ih_b, b_hh_b, bs_p);
  conv_pool<<<dim3(BATCH, (TSEQ + CTT - 1)/CTT), 256, 0, stream>>>(x, conv_w, conv_b, xseq_p);

  proj <<<dim3(4, HALF_A, 2), 512, 0, stream>>>(xseq_p, wih_p, bs_p, pre_p, 0);
  recur<<<dim3(16, 2), 512, 0, stream>>>(pre_p, whh_p, pool_p, stc_p, sth_p, 1, 0, HALF_A);
  proj <<<dim3(4, HALF_B, 2), 512, 0, stream>>>(xseq_p, wih_p, bs_p, pre_p, HALF_A);
  recur<<<dim3(16, 2), 512, 0, stream>>>(pre_p, whh_p, pool_p, stc_p, sth_p, 0, 1, HALF_B);

  fc<<<BATCH, 256, 0, stream>>>(pool_p, l1w, l1b, l2w, l2b, out);
}

// Round 8
// 599.855 us; speedup vs baseline: 1.2198x; 1.1910x over previous
//
#include <hip/hip_runtime.h>
#include <cstdio>

#define BATCH 256
#define TSEQ  393
#define CH    128
#define FIN   3
#define TIN   800
#define KK    15
#define HID   150
#define NPAD  640      // interleaved gate dim: n = 4*j + gate, j<160 (j>=150 pad)
#define KPAD  160      // padded hidden dim for W_hh
#define NB    16       // batch rows per recurrence block
#define PHASE 131      // 3 phases x 131 = 393
#define SLOTSTRIDE (256*640)    // halves between slots: [256 b][640 n]

typedef _Float16 half_t;
typedef __attribute__((ext_vector_type(8))) _Float16 h8v;
typedef __attribute__((ext_vector_type(4))) _Float16 h4v;
typedef __attribute__((ext_vector_type(4))) float f4v;

__device__ inline float hsig(float x){
  return __builtin_amdgcn_fmed3f(fmaf(0.2f, x, 0.5f), 0.f, 1.f);
}
__device__ inline float tanh_(float x){
  float e = __expf(2.f*x);
  return fmaf(-2.f, __builtin_amdgcn_rcpf(e + 1.f), 1.f);
}

// ================= setup: weight prep + conv fused (independent roles) =================
__global__ __launch_bounds__(256) void setup(const float* __restrict__ x,
    const float* __restrict__ conv_w, const float* __restrict__ conv_b,
    const float* __restrict__ wihf, const float* __restrict__ whhf,
    const float* __restrict__ bihf, const float* __restrict__ bhhf,
    const float* __restrict__ wihb, const float* __restrict__ whhb,
    const float* __restrict__ bihb, const float* __restrict__ bhhb,
    half_t* __restrict__ xseq, half_t* __restrict__ wih, half_t* __restrict__ whh,
    float* __restrict__ bsum){
  __shared__ float wl[CH*FIN*KK];
  __shared__ float xl[FIN][78];
  int bx = blockIdx.x, tid = threadIdx.x;
  if (bx < 3328){                       // conv1d+relu+maxpool2 -> xseq f16 [B][T][C]
    int b = bx & 255, t0 = (bx >> 8)*32;
    for (int i = tid; i < CH*FIN*KK; i += 256) wl[i] = conv_w[i];
    int p0 = 2*t0;
    for (int i = tid; i < FIN*78; i += 256){
      int f = i/78, q = i%78; int p = p0 + q;
      xl[f][q] = (p < TIN) ? x[((size_t)b*FIN + f)*TIN + p] : 0.f;
    }
    __syncthreads();
    int c = tid & 127, th = tid >> 7;
    float a0[16], a1[16];
    #pragma unroll
    for (int i=0;i<16;++i){ a0[i]=0.f; a1[i]=0.f; }
    #pragma unroll
    for (int f=0; f<FIN; ++f){
      float xv[46];
      #pragma unroll
      for (int q=0;q<46;++q) xv[q] = xl[f][th*32 + q];
      #pragma unroll
      for (int k=0;k<KK;++k){
        float ws = wl[c*FIN*KK + f*KK + k];
        #pragma unroll
        for (int i=0;i<16;++i){
          a0[i] = fmaf(xv[2*i+k],   ws, a0[i]);
          a1[i] = fmaf(xv[2*i+k+1], ws, a1[i]);
        }
      }
    }
    float bc = conv_b[c];
    #pragma unroll
    for (int i=0;i<16;++i){
      int t = t0 + th*16 + i;
      if (t < TSEQ){
        float v = fmaxf(fmaxf(a0[i], a1[i]) + bc, 0.f);
        xseq[((size_t)b*TSEQ + t)*CH + c] = (half_t)v;
      }
    }
    return;
  }
  bx -= 3328;
  if (bx < 640){                        // W_ih -> f16 gate-interleaved: n = 4j+g
    int i = bx*256 + tid;
    int c = i & 127; int n = (i >> 7) % NPAD; int d = i / (NPAD*CH);
    const float* src = d ? wihb : wihf;
    float v = 0.f;
    if (n < 600){ int j = n >> 2, g = n & 3; v = src[(g*HID + j)*CH + c]; }
    wih[i] = (half_t)v;
    return;
  }
  bx -= 640;
  if (bx < 800){                        // W_hh -> f16, canonical k cols
    int i = bx*256 + tid;
    int kc = i % KPAD; int n = (i / KPAD) % NPAD; int d = i / (NPAD*KPAD);
    const float* src = d ? whhb : whhf;
    float v = 0.f;
    if (n < 600 && kc < HID){ int j = n >> 2, g = n & 3; v = src[(g*HID + j)*HID + kc]; }
    whh[i] = (half_t)v;
    return;
  }
  { int i = (bx-800)*256 + tid;         // bias sum, interleaved
    if (i < 2*NPAD){
      int n = i % NPAD; int d = i / NPAD;
      float v = 0.f;
      if (n < 600){ int j = n >> 2, g = n & 3; int r = g*HID + j;
        v = d ? (bihb[r] + bhhb[r]) : (bihf[r] + bhhf[r]); }
      bsum[i] = v;
    }
  }
}

// ================= proj body (swapped operands: A=W_ih, B=x) =================
// D[n-rows][b-cols]: lane (b=ln&15, kg) holds n = tile*16 + kg*4 + r.
// pre layout: [d][slot][256 b][640 n] f16.
__device__ __forceinline__ void proj_body(const half_t* __restrict__ xseq,
    const half_t* __restrict__ wih, const float* __restrict__ bsum,
    half_t* __restrict__ pre, int off, int nproj, int idx){
  int bt4 = idx & 3; int rest = idx >> 2;
  int s = rest % nproj; int d = rest / nproj;
  int sg = s + off;
  int t = d ? (TSEQ-1 - sg) : sg;
  int tid = threadIdx.x, wv = tid >> 6, ln = tid & 63;
  int m = ln & 15, kg = ln >> 4;
  half_t* pslot = pre + ((size_t)d*PHASE + s)*SLOTSTRIDE;
  #pragma unroll
  for (int i = 0; i < 5; ++i){
    int nt = (wv*5 + i)*16;
    h8v bfr[4];
    #pragma unroll
    for (int ks = 0; ks < 4; ++ks)
      bfr[ks] = *(const h8v*)(wih + ((size_t)d*NPAD + nt + m)*CH + ks*32 + kg*8);
    f4v bs4 = *(const f4v*)(bsum + d*NPAD + nt + kg*4);
    #pragma unroll
    for (int ms = 0; ms < 4; ++ms){
      int b = bt4*64 + ms*16 + m;
      h8v ax[4];
      #pragma unroll
      for (int ks = 0; ks < 4; ++ks)
        ax[ks] = *(const h8v*)(xseq + ((size_t)b*TSEQ + t)*CH + ks*32 + kg*8);
      f4v acc = bs4;
      #pragma unroll
      for (int ks = 0; ks < 4; ++ks)
        acc = __builtin_amdgcn_mfma_f32_16x16x32_f16(bfr[ks], ax[ks], acc, 0, 0, 0);
      h4v hv = {(half_t)acc[0], (half_t)acc[1], (half_t)acc[2], (half_t)acc[3]};
      *(h4v*)(pslot + (size_t)b*640 + nt + kg*4) = hv;
    }
  }
}

__global__ __launch_bounds__(512) void proj_kernel(const half_t* __restrict__ xseq,
    const half_t* __restrict__ wih, const float* __restrict__ bsum,
    half_t* __restrict__ pre, int off, int nproj){
  proj_body(xseq, wih, bsum, pre, off, nproj, blockIdx.x);
}

// ================= recurrence (+fused next-phase proj on blocks >=32) =================
#define PIN4(R0,R1,R2,R3, V) asm volatile( \
  "v_accvgpr_write_b32 " R0 ", %0\n\t" \
  "v_accvgpr_write_b32 " R1 ", %1\n\t" \
  "v_accvgpr_write_b32 " R2 ", %2\n\t" \
  "v_accvgpr_write_b32 " R3 ", %3" \
  :: "v"(V[0]), "v"(V[1]), "v"(V[2]), "v"(V[3]) : R0, R1, R2, R3)

#define LP(I,KS, R0,R1,R2,R3) { \
  h8v w_ = *(const h8v*)(whh + ((size_t)d*NPAD + ((wv*5+(I))*16+m))*KPAD + (KS)*32 + kg*8); \
  f4v wf_; __builtin_memcpy(&wf_, &w_, 16); \
  PIN4(R0,R1,R2,R3, wf_); }

#define ACLOBS "a0","a1","a2","a3","a4","a5","a6","a7","a8","a9",\
"a10","a11","a12","a13","a14","a15","a16","a17","a18","a19",\
"a20","a21","a22","a23","a24","a25","a26","a27","a28","a29",\
"a30","a31","a32","a33","a34","a35","a36","a37","a38","a39",\
"a40","a41","a42","a43","a44","a45","a46","a47","a48","a49",\
"a50","a51","a52","a53","a54","a55","a56","a57","a58","a59",\
"a60","a61","a62","a63","a64","a65","a66","a67","a68","a69",\
"a70","a71","a72","a73","a74","a75","a76","a77","a78","a79",\
"a80","a81","a82","a83","a84","a85","a86","a87","a88","a89",\
"a90","a91","a92","a93","a94","a95","a96","a97","a98","a99"

__global__ __launch_bounds__(512, 2) void recur_fused(
    const half_t* __restrict__ preR, const half_t* __restrict__ whh,
    float* __restrict__ pooled, float* __restrict__ stateC, half_t* __restrict__ stateH,
    int first, int last,
    const half_t* __restrict__ xseq, const half_t* __restrict__ wih,
    const float* __restrict__ bsum, half_t* __restrict__ preW,
    int off_next, int nproj){
  __shared__ __align__(16) half_t hbuf[2*NB*168];   // [2][16 b][168 j]

  if (blockIdx.x >= 32){
    if (nproj > 0) proj_body(xseq, wih, bsum, preW, off_next, nproj, blockIdx.x - 32);
    return;
  }

  int tid = threadIdx.x, wv = tid >> 6, ln = tid & 63;
  int m = ln & 15, kg = ln >> 4;
  int bl = m;                       // batch-local (D col)
  int bt = blockIdx.x & 15, d = blockIdx.x >> 4;
  int b0 = bt*NB;
  int blk = d*16 + bt;

  // pin W_hh A-fragments into physical AGPRs: frag(T,ks) -> a[20T+4ks .. +3]
  LP(0,0,"a0","a1","a2","a3")    LP(0,1,"a4","a5","a6","a7")    LP(0,2,"a8","a9","a10","a11")
  LP(0,3,"a12","a13","a14","a15") LP(0,4,"a16","a17","a18","a19")
  LP(1,0,"a20","a21","a22","a23") LP(1,1,"a24","a25","a26","a27") LP(1,2,"a28","a29","a30","a31")
  LP(1,3,"a32","a33","a34","a35") LP(1,4,"a36","a37","a38","a39")
  LP(2,0,"a40","a41","a42","a43") LP(2,1,"a44","a45","a46","a47") LP(2,2,"a48","a49","a50","a51")
  LP(2,3,"a52","a53","a54","a55") LP(2,4,"a56","a57","a58","a59")
  LP(3,0,"a60","a61","a62","a63") LP(3,1,"a64","a65","a66","a67") LP(3,2,"a68","a69","a70","a71")
  LP(3,3,"a72","a73","a74","a75") LP(3,4,"a76","a77","a78","a79")
  LP(4,0,"a80","a81","a82","a83") LP(4,1,"a84","a85","a86","a87") LP(4,2,"a88","a89","a90","a91")
  LP(4,3,"a92","a93","a94","a95") LP(4,4,"a96","a97","a98","a99")

  // lane identity: cells j = (wv*5+T)*4 + kg, batch bl
  int jb = wv*20 + kg;              // + T*4

  float c_reg[5], hm_reg[5];
  if (first){
    for (int i = tid; i < 2*NB*168; i += 512) hbuf[i] = (half_t)0.f;
    #pragma unroll
    for (int T = 0; T < 5; ++T){ c_reg[T] = 0.f; hm_reg[T] = -1e30f; }
  } else {
    for (int i = tid; i < NB*168; i += 512) hbuf[i] = stateH[(size_t)blk*NB*168 + i];
    for (int i = tid; i < NB*168; i += 512) hbuf[NB*168 + i] = (half_t)0.f;
    const float* sc = stateC + ((size_t)blk*512 + tid)*10;
    #pragma unroll
    for (int T = 0; T < 5; ++T){ c_reg[T] = sc[T]; hm_reg[T] = sc[5+T]; }
  }
  __syncthreads();

  const half_t* pb = preR + (size_t)d*PHASE*SLOTSTRIDE + (size_t)b0*640;
  int pofl = bl*640 + wv*80 + kg*4;   // + T*16

  // depth-2 prefetch pipeline
  h4v curp[5], nA[5];
  #pragma unroll
  for (int T = 0; T < 5; ++T) curp[T] = *(const h4v*)(pb + pofl + T*16);
  {
    const half_t* p1 = pb + (size_t)SLOTSTRIDE;
    #pragma unroll
    for (int T = 0; T < 5; ++T) nA[T] = *(const h4v*)(p1 + pofl + T*16);
  }

  int p = 0;
  #pragma unroll 1
  for (int s = 0; s < PHASE; ++s){
    int s2 = (s+2 < PHASE) ? s+2 : PHASE-1;
    const half_t* p2 = pb + (size_t)s2*SLOTSTRIDE;
    h4v nB[5];
    #pragma unroll
    for (int T = 0; T < 5; ++T) nB[T] = *(const h4v*)(p2 + pofl + T*16);

    // B fragments from h buffer p: lane bl reads h[bl][k-chunks]
    const half_t* hrd = hbuf + p*NB*168 + bl*168;
    h8v ah0 = *(const h8v*)(hrd + 0*32 + kg*8);
    h8v ah1 = *(const h8v*)(hrd + 1*32 + kg*8);
    h8v ah2 = *(const h8v*)(hrd + 2*32 + kg*8);
    h8v ah3 = *(const h8v*)(hrd + 3*32 + kg*8);
    h8v ah4 = *(const h8v*)(hrd + 4*32 + kg*8);

    // acc preloaded with pre (C operand) -> saves the adds
    f4v acc0 = {(float)curp[0][0], (float)curp[0][1], (float)curp[0][2], (float)curp[0][3]};
    f4v acc1 = {(float)curp[1][0], (float)curp[1][1], (float)curp[1][2], (float)curp[1][3]};
    f4v acc2 = {(float)curp[2][0], (float)curp[2][1], (float)curp[2][2], (float)curp[2][3]};
    f4v acc3 = {(float)curp[3][0], (float)curp[3][1], (float)curp[3][2], (float)curp[3][3]};
    f4v acc4 = {(float)curp[4][0], (float)curp[4][1], (float)curp[4][2], (float)curp[4][3]};

    // 25 MFMAs: D/C = acc (VGPR), A = W (AGPR literal), B = h (VGPR). ks-major,
    // 5 independent chains. s_nop 1 covers VALU(acc init)->MFMA SrcC hazard;
    // trailing s_nop 7 x2 covers MFMA->VALU read.
    asm volatile(
      "s_nop 1\n\t"
      "v_mfma_f32_16x16x32_f16 %0, a[0:3], %5, %0\n\t"
      "v_mfma_f32_16x16x32_f16 %1, a[20:23], %5, %1\n\t"
      "v_mfma_f32_16x16x32_f16 %2, a[40:43], %5, %2\n\t"
      "v_mfma_f32_16x16x32_f16 %3, a[60:63], %5, %3\n\t"
      "v_mfma_f32_16x16x32_f16 %4, a[80:83], %5, %4\n\t"
      "v_mfma_f32_16x16x32_f16 %0, a[4:7], %6, %0\n\t"
      "v_mfma_f32_16x16x32_f16 %1, a[24:27], %6, %1\n\t"
      "v_mfma_f32_16x16x32_f16 %2, a[44:47], %6, %2\n\t"
      "v_mfma_f32_16x16x32_f16 %3, a[64:67], %6, %3\n\t"
      "v_mfma_f32_16x16x32_f16 %4, a[84:87], %6, %4\n\t"
      "v_mfma_f32_16x16x32_f16 %0, a[8:11], %7, %0\n\t"
      "v_mfma_f32_16x16x32_f16 %1, a[28:31], %7, %1\n\t"
      "v_mfma_f32_16x16x32_f16 %2, a[48:51], %7, %2\n\t"
      "v_mfma_f32_16x16x32_f16 %3, a[68:71], %7, %3\n\t"
      "v_mfma_f32_16x16x32_f16 %4, a[88:91], %7, %4\n\t"
      "v_mfma_f32_16x16x32_f16 %0, a[12:15], %8, %0\n\t"
      "v_mfma_f32_16x16x32_f16 %1, a[32:35], %8, %1\n\t"
      "v_mfma_f32_16x16x32_f16 %2, a[52:55], %8, %2\n\t"
      "v_mfma_f32_16x16x32_f16 %3, a[72:75], %8, %3\n\t"
      "v_mfma_f32_16x16x32_f16 %4, a[92:95], %8, %4\n\t"
      "v_mfma_f32_16x16x32_f16 %0, a[16:19], %9, %0\n\t"
      "v_mfma_f32_16x16x32_f16 %1, a[36:39], %9, %1\n\t"
      "v_mfma_f32_16x16x32_f16 %2, a[56:59], %9, %2\n\t"
      "v_mfma_f32_16x16x32_f16 %3, a[76:79], %9, %3\n\t"
      "v_mfma_f32_16x16x32_f16 %4, a[96:99], %9, %4\n\t"
      "s_nop 7\n\t"
      "s_nop 7"
      : "+v"(acc0), "+v"(acc1), "+v"(acc2), "+v"(acc3), "+v"(acc4)
      : "v"(ah0), "v"(ah1), "v"(ah2), "v"(ah3), "v"(ah4));
    __builtin_amdgcn_sched_barrier(0);

    // gates are lane-local: acc[r] = gate r (i,f,g,o) of cell j = jb + T*4
    half_t* hwr = hbuf + (p^1)*NB*168 + bl*168 + jb;
    #define GATE(A, T) { \
      float cn = hsig(A[1])*c_reg[T] + hsig(A[0])*tanh_(A[2]); \
      float hn = hsig(A[3])*tanh_(cn); \
      c_reg[T] = cn; hm_reg[T] = fmaxf(hm_reg[T], hn); \
      hwr[(T)*4] = (half_t)hn; }
    GATE(acc0, 0) GATE(acc1, 1) GATE(acc2, 2) GATE(acc3, 3) GATE(acc4, 4)
    #undef GATE

    #pragma unroll
    for (int T = 0; T < 5; ++T) curp[T] = nA[T];
    #pragma unroll
    for (int T = 0; T < 5; ++T) nA[T] = nB[T];

    // lgkm-only barrier (global prefetch stays in flight); re-clobber a0..a99
    asm volatile("s_waitcnt lgkmcnt(0)" ::: "memory", ACLOBS);
    __builtin_amdgcn_s_barrier();
    __builtin_amdgcn_sched_barrier(0);
    p ^= 1;
  }

  if (!last){
    for (int i = tid; i < NB*168; i += 512) stateH[(size_t)blk*NB*168 + i] = hbuf[p*NB*168 + i];
    float* sc = stateC + ((size_t)blk*512 + tid)*10;
    #pragma unroll
    for (int T = 0; T < 5; ++T){ sc[T] = c_reg[T]; sc[5+T] = hm_reg[T]; }
  } else {
    #pragma unroll
    for (int T = 0; T < 5; ++T){
      int j = jb + T*4;
      if (j < HID) pooled[(size_t)(b0 + bl)*300 + d*HID + j] = hm_reg[T];
    }
  }
}

// ================= final MLP + softmax =================
__global__ __launch_bounds__(256) void fc(const float* __restrict__ pooled,
                                          const float* __restrict__ w1, const float* __restrict__ b1,
                                          const float* __restrict__ w2, const float* __restrict__ b2,
                                          float* __restrict__ out){
  __shared__ float prow[300];
  __shared__ float ps[64][5];
  __shared__ float z[52];
  __shared__ float lg[12];
  int b = blockIdx.x, tid = threadIdx.x;
  for (int i = tid; i < 300; i += 256) prow[i] = pooled[(size_t)b*300 + i];
  __syncthreads();
  int j = tid & 63, seg = tid >> 6;
  float a = 0.f;
  if (j < 50){
    const float* wr = w1 + (size_t)j*300 + seg*75;
    const float* pr = prow + seg*75;
    #pragma unroll 5
    for (int k = 0; k < 75; ++k) a = fmaf(pr[k], wr[k], a);
  }
  ps[j][seg] = a;
  __syncthreads();
  if (tid < 50) z[tid] = fmaxf(ps[tid][0]+ps[tid][1]+ps[tid][2]+ps[tid][3] + b1[tid], 0.f);
  __syncthreads();
  if (tid < 10){
    float a2 = b2[tid];
    for (int k = 0; k < 50; ++k) a2 = fmaf(z[k], w2[tid*50 + k], a2);
    lg[tid] = a2;
  }
  __syncthreads();
  if (tid < 10){
    float mx = lg[0];
    #pragma unroll
    for (int k = 1; k < 10; ++k) mx = fmaxf(mx, lg[k]);
    float ssum = 0.f;
    #pragma unroll
    for (int k = 0; k < 10; ++k) ssum += __expf(lg[k] - mx);
    out[(size_t)b*10 + tid] = __expf(lg[tid] - mx) / ssum;
  }
}

extern "C" void kernel_launch(void* const* d_in, const int* in_sizes, int n_in,
                              void* d_out, int out_size, void* d_ws, size_t ws_size,
                              hipStream_t stream) {
  const float* x      = (const float*)d_in[0];
  const float* conv_w = (const float*)d_in[1];
  const float* conv_b = (const float*)d_in[2];
  const float* w_ih_f = (const float*)d_in[3];
  const float* w_hh_f = (const float*)d_in[4];
  const float* b_ih_f = (const float*)d_in[5];
  const float* b_hh_f = (const float*)d_in[6];
  const float* w_ih_b = (const float*)d_in[7];
  const float* w_hh_b = (const float*)d_in[8];
  const float* b_ih_b = (const float*)d_in[9];
  const float* b_hh_b = (const float*)d_in[10];
  const float* l1w = (const float*)d_in[11];
  const float* l1b = (const float*)d_in[12];
  const float* l2w = (const float*)d_in[13];
  const float* l2b = (const float*)d_in[14];
  float* out = (float*)d_out;

  char* ws = (char*)d_ws;
  size_t off = 0;
  auto alloc = [&](size_t bytes){ size_t o = off; off += (bytes + 255) & ~(size_t)255; return o; };
  size_t xseq_o = alloc((size_t)BATCH*TSEQ*CH*2);
  size_t preA_o = alloc((size_t)2*PHASE*SLOTSTRIDE*2);
  size_t preB_o = alloc((size_t)2*PHASE*SLOTSTRIDE*2);
  size_t wih_o  = alloc((size_t)2*NPAD*CH*2);
  size_t whh_o  = alloc((size_t)2*NPAD*KPAD*2);
  size_t bs_o   = alloc((size_t)2*NPAD*4);
  size_t pool_o = alloc((size_t)BATCH*300*4);
  size_t stc_o  = alloc((size_t)32*512*10*4);
  size_t sth_o  = alloc((size_t)32*NB*168*2);
  if (off > ws_size){
    fprintf(stderr, "[cnnblstm] WS TOO SMALL: need %zu have %zu\n", off, ws_size);
    return;
  }
  half_t* xseq_p = (half_t*)(ws + xseq_o);
  half_t* preA_p = (half_t*)(ws + preA_o);
  half_t* preB_p = (half_t*)(ws + preB_o);
  half_t* wih_p  = (half_t*)(ws + wih_o);
  half_t* whh_p  = (half_t*)(ws + whh_o);
  float*  bs_p   = (float*)(ws + bs_o);
  float*  pool_p = (float*)(ws + pool_o);
  float*  stc_p  = (float*)(ws + stc_o);
  half_t* sth_p  = (half_t*)(ws + sth_o);

  int projBlocks = 4*PHASE*2;   // 1048

  setup<<<3328 + 640 + 800 + 5, 256, 0, stream>>>(x, conv_w, conv_b,
      w_ih_f, w_hh_f, b_ih_f, b_hh_f, w_ih_b, w_hh_b, b_ih_b, b_hh_b,
      xseq_p, wih_p, whh_p, bs_p);
  proj_kernel<<<projBlocks, 512, 0, stream>>>(xseq_p, wih_p, bs_p, preA_p, 0, PHASE);
  // phase 0: recur on preA, proj phase1 -> preB on idle CUs
  recur_fused<<<32 + projBlocks, 512, 0, stream>>>(preA_p, whh_p, pool_p, stc_p, sth_p,
      1, 0, xseq_p, wih_p, bs_p, preB_p, PHASE, PHASE);
  // phase 1: recur on preB, proj phase2 -> preA
  recur_fused<<<32 + projBlocks, 512, 0, stream>>>(preB_p, whh_p, pool_p, stc_p, sth_p,
      0, 0, xseq_p, wih_p, bs_p, preA_p, 2*PHASE, PHASE);
  // phase 2: recur on preA only
  recur_fused<<<32, 512, 0, stream>>>(preA_p, whh_p, pool_p, stc_p, sth_p,
      0, 1, xseq_p, wih_p, bs_p, preB_p, 0, 0);

  fc<<<BATCH, 256, 0, stream>>>(pool_p, l1w, l1b, l2w, l2b, out);
}